// Round 3
// baseline (65.070 us; speedup 1.0000x reference)
//
#include <hip/hip_runtime.h>
#include <math.h>

// ---------------- problem constants (from setup_inputs) ----------------
// B=64, n_mel=80, T_mel=1000, N_dec=1000, T_enc=250, n_spk=128, n_aug=10, z=16
constexpr int NMEL  = 64 * 80 * 1000;   // 5,120,000 elems per mel tensor
constexpr int NAL   = 64 * 1000 * 250;  // 16,000,000 alignment elems
constexpr int NGATE = 64 * 1000;        // 64,000
constexpr int NKL   = 64 * 16;          // 1024

// ---------------- block-role partition (exact-cover, unrolled) ----------
// bid 0          : KL
// bid 1          : CE (speaker + aug)
// bid 2..9       : gate (8 blocks, grid-stride)
// bid 10..2509   : mel (2500 blocks, 2 float4/thread/stream exact)
// bid 2510..5634 : align (3125 blocks, 5 float4/thread exact)
#define BID_KL    0
#define BID_CE    1
#define BID_GATE  2
#define NB_GATE   8
#define BID_MEL   (BID_GATE + NB_GATE)          // 10
#define NB_MEL    2500                           // 2500*256*2 = 1,280,000 = NMEL/4
#define BID_AL    (BID_MEL + NB_MEL)             // 2510
#define NB_AL     3125                           // 3125*256*5 = 4,000,000 = NAL/4
#define NBLOCKS   (BID_AL + NB_AL)               // 5635

// ws layout (doubles), one slot per block partial -> NO atomics:
#define WS_MEL1  0        // 2500
#define WS_MEL2  2560     // 2500
#define WS_AL    5120     // 3125
#define WS_GATE  8256     // 8
#define WS_KL    8264
#define WS_SPK   8265
#define WS_AUG   8266

__device__ inline float wave_red_sum(float v) {
#pragma unroll
    for (int o = 32; o; o >>= 1) v += __shfl_down(v, o, 64);
    return v;
}

__device__ inline float bce_term(float x, float y) {
    return fmaxf(x, 0.0f) - x * y + log1pf(__expf(-fabsf(x)));
}

__global__ __launch_bounds__(256) void tac2_loss_main(
    const float* __restrict__ mel_out, const float* __restrict__ mel_post,
    const float* __restrict__ gate_out, const float* __restrict__ align,
    const float* __restrict__ r_mu,    const float* __restrict__ r_lv,
    const float* __restrict__ spk_out, const float* __restrict__ aug_out,
    const float* __restrict__ mel_tgt, const float* __restrict__ gate_tgt,
    const float* __restrict__ spk_tgt, const float* __restrict__ aug_tgt,
    double* __restrict__ ws)
{
    const int bid = blockIdx.x, tid = threadIdx.x;
    const int lane = tid & 63, wid = tid >> 6;

    if (bid >= BID_AL) {
        // ---- alignment: 5 float4/thread, exact cover, loads batched ----
        const int b2 = bid - BID_AL;
        const float4* a = (const float4*)align;
        const int base = b2 * (256 * 5) + tid;   // + k*256, k=0..4
        float4 v[5];
#pragma unroll
        for (int k = 0; k < 5; ++k) v[k] = a[base + k * 256];  // 5 loads in flight
        float s = 0.f;
#pragma unroll
        for (int k = 0; k < 5; ++k) {
            const int e0 = (base + k * 256) * 4;
            float vv[4] = {v[k].x, v[k].y, v[k].z, v[k].w};
#pragma unroll
            for (int j = 0; j < 4; ++j) {
                const int e = e0 + j;
                const int tt = e % 250;
                const int nn = (e / 250) % 1000;
                const float d = nn * (1.0f / 1000.0f) - tt * (1.0f / 250.0f);
                const float w = 1.0f - __expf(-2.5f * d * d);
                s = fmaf(vv[j], w, s);
            }
        }
        s = wave_red_sum(s);
        __shared__ float sm[4];
        if (lane == 0) sm[wid] = s;
        __syncthreads();
        if (tid == 0)
            ws[WS_AL + b2] = (double)sm[0] + (double)sm[1] +
                             (double)sm[2] + (double)sm[3];
    } else if (bid >= BID_MEL) {
        // ---- mel: 2 float4/thread/stream, 6 loads in flight ----
        const int b2 = bid - BID_MEL;
        const float4* a = (const float4*)mel_out;
        const float4* p = (const float4*)mel_post;
        const float4* t = (const float4*)mel_tgt;
        const int base = b2 * 512 + tid;         // + k*256, k=0..1
        float4 av0 = a[base], av1 = a[base + 256];
        float4 pv0 = p[base], pv1 = p[base + 256];
        float4 tv0 = t[base], tv1 = t[base + 256];
        float s1 = 0.f, s2 = 0.f, d;
        d = av0.x - tv0.x; s1 = fmaf(d, d, s1);
        d = av0.y - tv0.y; s1 = fmaf(d, d, s1);
        d = av0.z - tv0.z; s1 = fmaf(d, d, s1);
        d = av0.w - tv0.w; s1 = fmaf(d, d, s1);
        d = av1.x - tv1.x; s1 = fmaf(d, d, s1);
        d = av1.y - tv1.y; s1 = fmaf(d, d, s1);
        d = av1.z - tv1.z; s1 = fmaf(d, d, s1);
        d = av1.w - tv1.w; s1 = fmaf(d, d, s1);
        d = pv0.x - tv0.x; s2 = fmaf(d, d, s2);
        d = pv0.y - tv0.y; s2 = fmaf(d, d, s2);
        d = pv0.z - tv0.z; s2 = fmaf(d, d, s2);
        d = pv0.w - tv0.w; s2 = fmaf(d, d, s2);
        d = pv1.x - tv1.x; s2 = fmaf(d, d, s2);
        d = pv1.y - tv1.y; s2 = fmaf(d, d, s2);
        d = pv1.z - tv1.z; s2 = fmaf(d, d, s2);
        d = pv1.w - tv1.w; s2 = fmaf(d, d, s2);
        s1 = wave_red_sum(s1);
        s2 = wave_red_sum(s2);
        __shared__ float sm1[4], sm2[4];
        if (lane == 0) { sm1[wid] = s1; sm2[wid] = s2; }
        __syncthreads();
        if (tid == 0) {
            ws[WS_MEL1 + b2] = (double)sm1[0] + (double)sm1[1] +
                               (double)sm1[2] + (double)sm1[3];
            ws[WS_MEL2 + b2] = (double)sm2[0] + (double)sm2[1] +
                               (double)sm2[2] + (double)sm2[3];
        }
    } else if (bid >= BID_GATE) {
        // ---- gate BCE: 8 blocks, grid-stride over 16,000 float4 ----
        const int b2 = bid - BID_GATE;
        const float4* x4 = (const float4*)gate_out;
        const float4* y4 = (const float4*)gate_tgt;
        float s = 0.f;
        for (int i = b2 * 256 + tid; i < NGATE / 4; i += NB_GATE * 256) {
            float4 x = x4[i], y = y4[i];
            s += bce_term(x.x, y.x) + bce_term(x.y, y.y) +
                 bce_term(x.z, y.z) + bce_term(x.w, y.w);
        }
        s = wave_red_sum(s);
        __shared__ float sm[4];
        if (lane == 0) sm[wid] = s;
        __syncthreads();
        if (tid == 0)
            ws[WS_GATE + b2] = (double)sm[0] + (double)sm[1] +
                               (double)sm[2] + (double)sm[3];
    } else if (bid == BID_KL) {
        // ---- KL: sum(1 + lv - mu^2 - exp(lv)), 1024 elems ----
        float s = 0.f;
        for (int i = tid; i < NKL; i += 256) {
            const float mu = r_mu[i], lv = r_lv[i];
            s += 1.0f + lv - mu * mu - __expf(lv);
        }
        s = wave_red_sum(s);
        __shared__ float sm[4];
        if (lane == 0) sm[wid] = s;
        __syncthreads();
        if (tid == 0)
            ws[WS_KL] = (double)sm[0] + (double)sm[1] +
                        (double)sm[2] + (double)sm[3];
    } else {
        // ---- CE: one wave per row; rows strided across 4 waves ----
        float spk_s = 0.f, aug_s = 0.f;
        for (int b = wid; b < 64; b += 4) {
            { // speaker: 128 cols -> 2 per lane
                const float* xo = spk_out + b * 128;
                const float* xt = spk_tgt + b * 128;
                const float x0 = xo[lane], x1 = xo[lane + 64];
                const float t0 = xt[lane], t1 = xt[lane + 64];
                float bv; int bi;
                if (t0 >= t1) { bv = t0; bi = lane; } else { bv = t1; bi = lane + 64; }
#pragma unroll
                for (int o = 32; o; o >>= 1) {
                    const float ov = __shfl_xor(bv, o, 64);
                    const int   oi = __shfl_xor(bi, o, 64);
                    if (ov > bv || (ov == bv && oi < bi)) { bv = ov; bi = oi; }
                }
                float m = fmaxf(x0, x1);
#pragma unroll
                for (int o = 32; o; o >>= 1) m = fmaxf(m, __shfl_xor(m, o, 64));
                float e = __expf(x0 - m) + __expf(x1 - m);
#pragma unroll
                for (int o = 32; o; o >>= 1) e += __shfl_xor(e, o, 64);
                if (lane == 0) spk_s += m + logf(e) - xo[bi];
            }
            { // aug: 10 cols
                const float* ao = aug_out + b * 10;
                const float* at = aug_tgt + b * 10;
                const float x  = (lane < 10) ? ao[lane] : -INFINITY;
                float bv = (lane < 10) ? at[lane] : -INFINITY;
                int   bi = (lane < 10) ? lane : (1 << 30);
#pragma unroll
                for (int o = 32; o; o >>= 1) {
                    const float ov = __shfl_xor(bv, o, 64);
                    const int   oi = __shfl_xor(bi, o, 64);
                    if (ov > bv || (ov == bv && oi < bi)) { bv = ov; bi = oi; }
                }
                float m = x;
#pragma unroll
                for (int o = 32; o; o >>= 1) m = fmaxf(m, __shfl_xor(m, o, 64));
                float e = (lane < 10) ? __expf(x - m) : 0.0f;
#pragma unroll
                for (int o = 32; o; o >>= 1) e += __shfl_xor(e, o, 64);
                if (lane == 0) aug_s += m + logf(e) - ao[bi];
            }
        }
        __shared__ double ce_sm[4][2];
        if (lane == 0) { ce_sm[wid][0] = (double)spk_s; ce_sm[wid][1] = (double)aug_s; }
        __syncthreads();
        if (tid == 0) {
            ws[WS_SPK] = ce_sm[0][0] + ce_sm[1][0] + ce_sm[2][0] + ce_sm[3][0];
            ws[WS_AUG] = ce_sm[0][1] + ce_sm[1][1] + ce_sm[2][1] + ce_sm[3][1];
        }
    }
}

// reduce one double array of length n with the whole block, fixed order
__device__ inline double block_red_d(const double* __restrict__ p, int n,
                                     double* sd) {
    const int tid = threadIdx.x;
    double s = 0.0;
    for (int i = tid; i < n; i += 256) s += p[i];
#pragma unroll
    for (int o = 32; o; o >>= 1) s += __shfl_down(s, o, 64);
    const int lane = tid & 63, wid = tid >> 6;
    __syncthreads();
    if (lane == 0) sd[wid] = s;
    __syncthreads();
    double r = sd[0] + sd[1] + sd[2] + sd[3];
    return r;
}

__global__ __launch_bounds__(256) void tac2_loss_final(
    const double* __restrict__ ws, const int* __restrict__ step_p,
    float* __restrict__ out)
{
    __shared__ double sd[4];
    const double s_mel1 = block_red_d(ws + WS_MEL1, NB_MEL, sd);
    const double s_mel2 = block_red_d(ws + WS_MEL2, NB_MEL, sd);
    const double s_al   = block_red_d(ws + WS_AL, NB_AL, sd);
    const double s_gate = block_red_d(ws + WS_GATE, NB_GATE, sd);

    if (threadIdx.x == 0) {
        const double mel   = s_mel1 / (double)NMEL + s_mel2 / (double)NMEL;
        const double gate  = s_gate / (double)NGATE;
        const double kl    = -0.5 * ws[WS_KL];
        const double alo   = fabs(s_al);
        const double spk   = ws[WS_SPK] / 64.0;
        const double aug   = ws[WS_AUG] / 64.0;
        const double step  = (double)step_p[0];
        const double w     = 1.0 / (1.0 + exp(-0.0025 * (step - 10000.0)));
        const double total = 10.0 * (mel + gate) + 0.01 * (kl * w) +
                             0.1 * spk + 0.1 * aug + 0.0005 * alo;
        out[0] = (float)total;
        out[1] = (float)(mel + gate);
        out[2] = (float)kl;
        out[3] = (float)w;
        out[4] = (float)spk;
        out[5] = (float)aug;
        out[6] = (float)alo;
    }
}

extern "C" void kernel_launch(void* const* d_in, const int* in_sizes, int n_in,
                              void* d_out, int out_size, void* d_ws, size_t ws_size,
                              hipStream_t stream) {
    const float* mel_out  = (const float*)d_in[0];
    const float* mel_post = (const float*)d_in[1];
    const float* gate_out = (const float*)d_in[2];
    const float* align    = (const float*)d_in[3];
    const float* r_mu     = (const float*)d_in[4];
    const float* r_lv     = (const float*)d_in[5];
    const float* spk_out  = (const float*)d_in[6];
    const float* aug_out  = (const float*)d_in[7];
    const float* mel_tgt  = (const float*)d_in[8];
    const float* gate_tgt = (const float*)d_in[9];
    const float* spk_tgt  = (const float*)d_in[10];
    const float* aug_tgt  = (const float*)d_in[11];
    const int*   step_p   = (const int*)d_in[12];

    double* ws = (double*)d_ws;

    tac2_loss_main<<<NBLOCKS, 256, 0, stream>>>(
        mel_out, mel_post, gate_out, align, r_mu, r_lv, spk_out, aug_out,
        mel_tgt, gate_tgt, spk_tgt, aug_tgt, ws);

    tac2_loss_final<<<1, 256, 0, stream>>>(ws, step_p, (float*)d_out);
}

// Round 4
// 60.078 us; speedup vs baseline: 1.0831x; 1.0831x over previous
//
#include <hip/hip_runtime.h>
#include <math.h>

// ---------------- problem constants (from setup_inputs) ----------------
// B=64, n_mel=80, T_mel=1000, N_dec=1000, T_enc=250, n_spk=128, n_aug=10, z=16
constexpr int NMEL  = 64 * 80 * 1000;   // 5,120,000 elems per mel tensor
constexpr int NAL   = 64 * 1000 * 250;  // 16,000,000 alignment elems
constexpr int NGATE = 64 * 1000;        // 64,000
constexpr int NKL   = 64 * 16;          // 1024

// ---------------- block-role partition (all-resident, zero churn) -------
// 1256 workgroups total (~4.9/CU):
//   bid in [0,1250): even -> mel WG (bid>>1), odd -> align WG (bid>>1)
//     mel   WG: 8 float4/thread/stream (24 loads), exact cover 625*2048=NMEL/4
//     align WG: 25 float4/thread (25 loads),       exact cover 625*6400=NAL/4
//   bid 1250..1253 : gate (4 WGs, grid-stride)
//   bid 1254       : KL
//   bid 1255       : CE (speaker + aug)
#define NB_MEL    625
#define NB_AL     625
#define BID_GATE  1250
#define NB_GATE   4
#define BID_KL    1254
#define BID_CE    1255
#define NBLOCKS   1256

// ws layout (doubles), one slot per block partial -> NO atomics:
#define WS_MEL1  0        // 625
#define WS_MEL2  640      // 625
#define WS_AL    1280     // 625
#define WS_GATE  1920     // 4
#define WS_KL    1924
#define WS_SPK   1925
#define WS_AUG   1926

__device__ inline float wave_red_sum(float v) {
#pragma unroll
    for (int o = 32; o; o >>= 1) v += __shfl_down(v, o, 64);
    return v;
}

__device__ inline void block_store1(float v, double* dst, float* sm,
                                    int lane, int wid, int tid) {
    v = wave_red_sum(v);
    if (lane == 0) sm[wid] = v;
    __syncthreads();
    if (tid == 0)
        *dst = (double)sm[0] + (double)sm[1] + (double)sm[2] + (double)sm[3];
}

__device__ inline float bce_term(float x, float y) {
    return fmaxf(x, 0.0f) - x * y + log1pf(__expf(-fabsf(x)));
}

__global__ __launch_bounds__(256) void tac2_loss_main(
    const float* __restrict__ mel_out, const float* __restrict__ mel_post,
    const float* __restrict__ gate_out, const float* __restrict__ align,
    const float* __restrict__ r_mu,    const float* __restrict__ r_lv,
    const float* __restrict__ spk_out, const float* __restrict__ aug_out,
    const float* __restrict__ mel_tgt, const float* __restrict__ gate_tgt,
    const float* __restrict__ spk_tgt, const float* __restrict__ aug_tgt,
    double* __restrict__ ws)
{
    __shared__ float sm[4];
    __shared__ float sm2[4];
    const int bid = blockIdx.x, tid = threadIdx.x;
    const int lane = tid & 63, wid = tid >> 6;

    if (bid < 1250) {
        const int sub = bid >> 1;
        if ((bid & 1) == 0) {
            // ---- mel: 8 float4/thread/stream, 4 chunks of 6 loads ----
            const float4* a = (const float4*)mel_out;
            const float4* p = (const float4*)mel_post;
            const float4* t = (const float4*)mel_tgt;
            int i = sub * 2048 + tid;
            float s1 = 0.f, s2 = 0.f;
#pragma unroll
            for (int c = 0; c < 4; ++c) {
                const float4 a0 = a[i], a1 = a[i + 256];
                const float4 p0 = p[i], p1 = p[i + 256];
                const float4 t0 = t[i], t1 = t[i + 256];
                float d;
                d = a0.x - t0.x; s1 = fmaf(d, d, s1);
                d = a0.y - t0.y; s1 = fmaf(d, d, s1);
                d = a0.z - t0.z; s1 = fmaf(d, d, s1);
                d = a0.w - t0.w; s1 = fmaf(d, d, s1);
                d = a1.x - t1.x; s1 = fmaf(d, d, s1);
                d = a1.y - t1.y; s1 = fmaf(d, d, s1);
                d = a1.z - t1.z; s1 = fmaf(d, d, s1);
                d = a1.w - t1.w; s1 = fmaf(d, d, s1);
                d = p0.x - t0.x; s2 = fmaf(d, d, s2);
                d = p0.y - t0.y; s2 = fmaf(d, d, s2);
                d = p0.z - t0.z; s2 = fmaf(d, d, s2);
                d = p0.w - t0.w; s2 = fmaf(d, d, s2);
                d = p1.x - t1.x; s2 = fmaf(d, d, s2);
                d = p1.y - t1.y; s2 = fmaf(d, d, s2);
                d = p1.z - t1.z; s2 = fmaf(d, d, s2);
                d = p1.w - t1.w; s2 = fmaf(d, d, s2);
                i += 512;
            }
            s1 = wave_red_sum(s1);
            s2 = wave_red_sum(s2);
            if (lane == 0) { sm[wid] = s1; sm2[wid] = s2; }
            __syncthreads();
            if (tid == 0) {
                ws[WS_MEL1 + sub] = (double)sm[0] + (double)sm[1] +
                                    (double)sm[2] + (double)sm[3];
                ws[WS_MEL2 + sub] = (double)sm2[0] + (double)sm2[1] +
                                    (double)sm2[2] + (double)sm2[3];
            }
        } else {
            // ---- align: 25 float4/thread, 5 chunks of 5 loads ----
            const float4* al = (const float4*)align;
            int i = sub * 6400 + tid;
            float s = 0.f;
#pragma unroll
            for (int c = 0; c < 5; ++c) {
                const float4 v0 = al[i];
                const float4 v1 = al[i + 256];
                const float4 v2 = al[i + 512];
                const float4 v3 = al[i + 768];
                const float4 v4 = al[i + 1024];
                const float4 vv[5] = {v0, v1, v2, v3, v4};
#pragma unroll
                for (int k = 0; k < 5; ++k) {
                    const int e0 = (i + k * 256) * 4;
                    const float f[4] = {vv[k].x, vv[k].y, vv[k].z, vv[k].w};
#pragma unroll
                    for (int j = 0; j < 4; ++j) {
                        const int e = e0 + j;
                        const int tt = e % 250;
                        const int nn = (e / 250) % 1000;
                        const float d = nn * (1.0f / 1000.0f) - tt * (1.0f / 250.0f);
                        const float w = 1.0f - __expf(-2.5f * d * d);
                        s = fmaf(f[j], w, s);
                    }
                }
                i += 1280;
            }
            block_store1(s, ws + WS_AL + sub, sm, lane, wid, tid);
        }
    } else if (bid < BID_GATE + NB_GATE) {
        // ---- gate BCE: 4 blocks, grid-stride over 16,000 float4 ----
        const int b2 = bid - BID_GATE;
        const float4* x4 = (const float4*)gate_out;
        const float4* y4 = (const float4*)gate_tgt;
        float s = 0.f;
        for (int i = b2 * 256 + tid; i < NGATE / 4; i += NB_GATE * 256) {
            float4 x = x4[i], y = y4[i];
            s += bce_term(x.x, y.x) + bce_term(x.y, y.y) +
                 bce_term(x.z, y.z) + bce_term(x.w, y.w);
        }
        block_store1(s, ws + WS_GATE + b2, sm, lane, wid, tid);
    } else if (bid == BID_KL) {
        // ---- KL: sum(1 + lv - mu^2 - exp(lv)), 1024 elems ----
        float s = 0.f;
        for (int i = tid; i < NKL; i += 256) {
            const float mu = r_mu[i], lv = r_lv[i];
            s += 1.0f + lv - mu * mu - __expf(lv);
        }
        block_store1(s, ws + WS_KL, sm, lane, wid, tid);
    } else {
        // ---- CE: one wave per row; rows strided across 4 waves ----
        float spk_s = 0.f, aug_s = 0.f;
        for (int b = wid; b < 64; b += 4) {
            { // speaker: 128 cols -> 2 per lane
                const float* xo = spk_out + b * 128;
                const float* xt = spk_tgt + b * 128;
                const float x0 = xo[lane], x1 = xo[lane + 64];
                const float t0 = xt[lane], t1 = xt[lane + 64];
                float bv; int bi;
                if (t0 >= t1) { bv = t0; bi = lane; } else { bv = t1; bi = lane + 64; }
#pragma unroll
                for (int o = 32; o; o >>= 1) {
                    const float ov = __shfl_xor(bv, o, 64);
                    const int   oi = __shfl_xor(bi, o, 64);
                    if (ov > bv || (ov == bv && oi < bi)) { bv = ov; bi = oi; }
                }
                float m = fmaxf(x0, x1);
#pragma unroll
                for (int o = 32; o; o >>= 1) m = fmaxf(m, __shfl_xor(m, o, 64));
                float e = __expf(x0 - m) + __expf(x1 - m);
#pragma unroll
                for (int o = 32; o; o >>= 1) e += __shfl_xor(e, o, 64);
                if (lane == 0) spk_s += m + logf(e) - xo[bi];
            }
            { // aug: 10 cols
                const float* ao = aug_out + b * 10;
                const float* at = aug_tgt + b * 10;
                const float x  = (lane < 10) ? ao[lane] : -INFINITY;
                float bv = (lane < 10) ? at[lane] : -INFINITY;
                int   bi = (lane < 10) ? lane : (1 << 30);
#pragma unroll
                for (int o = 32; o; o >>= 1) {
                    const float ov = __shfl_xor(bv, o, 64);
                    const int   oi = __shfl_xor(bi, o, 64);
                    if (ov > bv || (ov == bv && oi < bi)) { bv = ov; bi = oi; }
                }
                float m = x;
#pragma unroll
                for (int o = 32; o; o >>= 1) m = fmaxf(m, __shfl_xor(m, o, 64));
                float e = (lane < 10) ? __expf(x - m) : 0.0f;
#pragma unroll
                for (int o = 32; o; o >>= 1) e += __shfl_xor(e, o, 64);
                if (lane == 0) aug_s += m + logf(e) - ao[bi];
            }
        }
        __shared__ double ce_sm[4][2];
        if (lane == 0) { ce_sm[wid][0] = (double)spk_s; ce_sm[wid][1] = (double)aug_s; }
        __syncthreads();
        if (tid == 0) {
            ws[WS_SPK] = ce_sm[0][0] + ce_sm[1][0] + ce_sm[2][0] + ce_sm[3][0];
            ws[WS_AUG] = ce_sm[0][1] + ce_sm[1][1] + ce_sm[2][1] + ce_sm[3][1];
        }
    }
}

// reduce one double array of length n with the whole block, fixed order
__device__ inline double block_red_d(const double* __restrict__ p, int n,
                                     double* sd) {
    const int tid = threadIdx.x;
    double s = 0.0;
    for (int i = tid; i < n; i += 256) s += p[i];
#pragma unroll
    for (int o = 32; o; o >>= 1) s += __shfl_down(s, o, 64);
    const int lane = tid & 63, wid = tid >> 6;
    __syncthreads();
    if (lane == 0) sd[wid] = s;
    __syncthreads();
    return sd[0] + sd[1] + sd[2] + sd[3];
}

__global__ __launch_bounds__(256) void tac2_loss_final(
    const double* __restrict__ ws, const int* __restrict__ step_p,
    float* __restrict__ out)
{
    __shared__ double sd[4];
    const double s_mel1 = block_red_d(ws + WS_MEL1, NB_MEL, sd);
    const double s_mel2 = block_red_d(ws + WS_MEL2, NB_MEL, sd);
    const double s_al   = block_red_d(ws + WS_AL, NB_AL, sd);
    const double s_gate = block_red_d(ws + WS_GATE, NB_GATE, sd);

    if (threadIdx.x == 0) {
        const double mel   = s_mel1 / (double)NMEL + s_mel2 / (double)NMEL;
        const double gate  = s_gate / (double)NGATE;
        const double kl    = -0.5 * ws[WS_KL];
        const double alo   = fabs(s_al);
        const double spk   = ws[WS_SPK] / 64.0;
        const double aug   = ws[WS_AUG] / 64.0;
        const double step  = (double)step_p[0];
        const double w     = 1.0 / (1.0 + exp(-0.0025 * (step - 10000.0)));
        const double total = 10.0 * (mel + gate) + 0.01 * (kl * w) +
                             0.1 * spk + 0.1 * aug + 0.0005 * alo;
        out[0] = (float)total;
        out[1] = (float)(mel + gate);
        out[2] = (float)kl;
        out[3] = (float)w;
        out[4] = (float)spk;
        out[5] = (float)aug;
        out[6] = (float)alo;
    }
}

extern "C" void kernel_launch(void* const* d_in, const int* in_sizes, int n_in,
                              void* d_out, int out_size, void* d_ws, size_t ws_size,
                              hipStream_t stream) {
    const float* mel_out  = (const float*)d_in[0];
    const float* mel_post = (const float*)d_in[1];
    const float* gate_out = (const float*)d_in[2];
    const float* align    = (const float*)d_in[3];
    const float* r_mu     = (const float*)d_in[4];
    const float* r_lv     = (const float*)d_in[5];
    const float* spk_out  = (const float*)d_in[6];
    const float* aug_out  = (const float*)d_in[7];
    const float* mel_tgt  = (const float*)d_in[8];
    const float* gate_tgt = (const float*)d_in[9];
    const float* spk_tgt  = (const float*)d_in[10];
    const float* aug_tgt  = (const float*)d_in[11];
    const int*   step_p   = (const int*)d_in[12];

    double* ws = (double*)d_ws;

    tac2_loss_main<<<NBLOCKS, 256, 0, stream>>>(
        mel_out, mel_post, gate_out, align, r_mu, r_lv, spk_out, aug_out,
        mel_tgt, gate_tgt, spk_tgt, aug_tgt, ws);

    tac2_loss_final<<<1, 256, 0, stream>>>(ws, step_p, (float*)d_out);
}